// Round 12
// baseline (736.682 us; speedup 1.0000x reference)
//
#include <hip/hip_runtime.h>
#include <math.h>

// ---------------- problem constants ----------------
#define B_    8
#define H_    56
#define W_    56
#define HW_   3136
#define C0_   256
#define C1_   512
#define C2_   1024
#define DIN_  1794      // raw conv_w K (includes 2 coord cols, folded into epilogue)
#define KD_   1792      // descriptor K (GEMM K), 56 chunks of 32
#define KCP_  56        // phi K-chunks
#define DOUT_ 448
#define NCHP_ 28        // phi N-chunks (448/16)
#define NC_   3136      // centers
#define NCHD_ 196       // dist N-chunks (3136/16)
#define NCPAD_ 200      // padded to 4 quarters of 50
#define QCH_  50        // N-chunks per quarter
#define KCD_  14        // dist K-chunks (448/32)
#define DTS_  452       // LDS D-tile row stride (floats)
#define PCH_  28672     // phip chunk stride in shorts (in-place alias of desc pixels)
#define CHS_  7168      // one B-chunk in shorts (14*512)

typedef __attribute__((ext_vector_type(8))) short bh8;
typedef __attribute__((ext_vector_type(4))) float f32x4;

__device__ __forceinline__ short f2bf(float f) {
  union { float f; unsigned u; } v; v.f = f;
  unsigned r = v.u + 0x7fffu + ((v.u >> 16) & 1u);
  return (short)(r >> 16);
}
__device__ __forceinline__ float bf2f(short s) {
  union { unsigned u; float f; } v; v.u = ((unsigned)(unsigned short)s) << 16;
  return v.f;
}

// ======== desc0: pool(p0) -> desc[:, 0:256], transposed, bf16 ========
__global__ __launch_bounds__(256) void desc0_kernel(const float* __restrict__ p0,
                                                    short* __restrict__ desc) {
  __shared__ float sv[64 * 57];
  const int c0 = blockIdx.x * 64, h = blockIdx.y, b = blockIdx.z;
  for (int item = threadIdx.x; item < 64 * 56; item += 256) {
    int x = item % 56, c = item / 56;
    const float* src = p0 + (((size_t)(b * C0_ + c0 + c)) * 56 + h) * 56 + x;
    float s = src[0];
    if (h > 0)  s += src[-56];
    if (h < 55) s += src[56];
    sv[c * 57 + x] = s;
  }
  __syncthreads();
  for (int item = threadIdx.x; item < 56 * 8; item += 256) {
    int g = item & 7, w = item >> 3;
    bh8 o;
#pragma unroll
    for (int j = 0; j < 8; ++j) {
      const float* s0 = sv + (g * 8 + j) * 57;
      float v = s0[w];
      if (w > 0)  v += s0[w - 1];
      if (w < 55) v += s0[w + 1];
      o[j] = f2bf(v * (1.0f / 9.0f));
    }
    size_t pid = (size_t)b * HW_ + h * 56 + w;
    *(bh8*)(desc + pid * KD_ + c0 + g * 8) = o;
  }
}

// ======== desc1: pool(p1)+bilinear x2 -> desc[:, 256:768] ========
__global__ __launch_bounds__(256) void desc1_kernel(const float* __restrict__ p1,
                                                    short* __restrict__ desc) {
  __shared__ float sv[2 * 64 * 29];
  const int c0 = blockIdx.x * 64, h = blockIdx.y, b = blockIdx.z;
  float sy = (h + 0.5f) * 0.5f - 0.5f;
  float fyf = floorf(sy);
  float fy = sy - fyf;
  int iy = (int)fyf;
  int pya = min(max(iy, 0), 27), pyb = min(max(iy + 1, 0), 27);
  for (int item = threadIdx.x; item < 64 * 2 * 28; item += 256) {
    int x = item % 28;
    int pr = (item / 28) & 1;
    int c = item / 56;
    int r = pr ? pyb : pya;
    const float* src = p1 + (((size_t)(b * C1_ + c0 + c)) * 28 + r) * 28 + x;
    float s = src[0];
    if (r > 0)  s += src[-28];
    if (r < 27) s += src[28];
    sv[pr * (64 * 29) + c * 29 + x] = s;
  }
  __syncthreads();
  for (int item = threadIdx.x; item < 56 * 8; item += 256) {
    int g = item & 7, w = item >> 3;
    float sx = (w + 0.5f) * 0.5f - 0.5f;
    float fxf = floorf(sx);
    float fx = sx - fxf;
    int ix = (int)fxf;
    int x0 = min(max(ix, 0), 27), x1 = min(max(ix + 1, 0), 27);
    bh8 o;
#pragma unroll
    for (int j = 0; j < 8; ++j) {
      const float* s0 = sv + (g * 8 + j) * 29;
      const float* s1 = s0 + 64 * 29;
      float p00 = s0[x0] + (x0 > 0 ? s0[x0 - 1] : 0.f) + (x0 < 27 ? s0[x0 + 1] : 0.f);
      float p01 = s0[x1] + (x1 > 0 ? s0[x1 - 1] : 0.f) + (x1 < 27 ? s0[x1 + 1] : 0.f);
      float p10 = s1[x0] + (x0 > 0 ? s1[x0 - 1] : 0.f) + (x0 < 27 ? s1[x0 + 1] : 0.f);
      float p11 = s1[x1] + (x1 > 0 ? s1[x1 - 1] : 0.f) + (x1 < 27 ? s1[x1 + 1] : 0.f);
      float top = p00 + fx * (p01 - p00);
      float bot = p10 + fx * (p11 - p10);
      o[j] = f2bf((top + fy * (bot - top)) * (1.0f / 9.0f));
    }
    size_t pid = (size_t)b * HW_ + h * 56 + w;
    *(bh8*)(desc + pid * KD_ + C0_ + c0 + g * 8) = o;
  }
}

// ======== desc2: pool(p2)+bilinear x4 -> desc[:, 768:1792] ========
__global__ __launch_bounds__(256) void desc2_kernel(const float* __restrict__ p2,
                                                    short* __restrict__ desc) {
  __shared__ float sv[2 * 64 * 15];
  const int c0 = blockIdx.x * 64, h = blockIdx.y, b = blockIdx.z;
  float sy = (h + 0.5f) * 0.25f - 0.5f;
  float fyf = floorf(sy);
  float fy = sy - fyf;
  int iy = (int)fyf;
  int pya = min(max(iy, 0), 13), pyb = min(max(iy + 1, 0), 13);
  for (int item = threadIdx.x; item < 64 * 2 * 14; item += 256) {
    int x = item % 14;
    int pr = (item / 14) & 1;
    int c = item / 28;
    int r = pr ? pyb : pya;
    const float* src = p2 + (((size_t)(b * C2_ + c0 + c)) * 14 + r) * 14 + x;
    float s = src[0];
    if (r > 0)  s += src[-14];
    if (r < 13) s += src[14];
    sv[pr * (64 * 15) + c * 15 + x] = s;
  }
  __syncthreads();
  for (int item = threadIdx.x; item < 56 * 8; item += 256) {
    int g = item & 7, w = item >> 3;
    float sx = (w + 0.5f) * 0.25f - 0.5f;
    float fxf = floorf(sx);
    float fx = sx - fxf;
    int ix = (int)fxf;
    int x0 = min(max(ix, 0), 13), x1 = min(max(ix + 1, 0), 13);
    bh8 o;
#pragma unroll
    for (int j = 0; j < 8; ++j) {
      const float* s0 = sv + (g * 8 + j) * 15;
      const float* s1 = s0 + 64 * 15;
      float p00 = s0[x0] + (x0 > 0 ? s0[x0 - 1] : 0.f) + (x0 < 13 ? s0[x0 + 1] : 0.f);
      float p01 = s0[x1] + (x1 > 0 ? s0[x1 - 1] : 0.f) + (x1 < 13 ? s0[x1 + 1] : 0.f);
      float p10 = s1[x0] + (x0 > 0 ? s1[x0 - 1] : 0.f) + (x0 < 13 ? s1[x0 + 1] : 0.f);
      float p11 = s1[x1] + (x1 > 0 ? s1[x1 - 1] : 0.f) + (x1 < 13 ? s1[x1 + 1] : 0.f);
      float top = p00 + fx * (p01 - p00);
      float bot = p10 + fx * (p11 - p10);
      o[j] = f2bf((top + fy * (bot - top)) * (1.0f / 9.0f));
    }
    size_t pid = (size_t)b * HW_ + h * 56 + w;
    *(bh8*)(desc + pid * KD_ + C0_ + C1_ + c0 + g * 8) = o;
  }
}

// ---------------- |c_j|^2 (bf16-rounded), padded: j>=NC_ -> 1e30 ----------------
__global__ void cent2_kernel(const float* __restrict__ C, float* __restrict__ c2) {
  int j = blockIdx.x * blockDim.x + threadIdx.x;
  if (j >= NCPAD_ * 16) return;
  if (j >= NC_) { c2[j] = 1e30f; return; }
  float s = 0.f;
  for (int d = 0; d < DOUT_; ++d) {
    float v = bf2f(f2bf(C[(size_t)d * NC_ + j]));
    s = fmaf(v, v, s);
  }
  c2[j] = s;
}

// ---------------- pack C into B-frag layout, padded to 200 N-chunks ----------------
__global__ void cpack_kernel(const float* __restrict__ C, short* __restrict__ Cpk) {
  int idx = blockIdx.x * 256 + threadIdx.x;       // NCPAD_*KCD_*64 = 179200 exact
  int ln = idx & 63;
  int kc = (idx >> 6) % KCD_;
  int nc = idx / (KCD_ * 64);
  int n  = nc * 16 + (ln & 15);
  int k0 = kc * 32 + ((ln >> 4) << 3);
  bh8 o;
#pragma unroll
  for (int j = 0; j < 8; ++j) o[j] = (n < NC_) ? f2bf(C[(size_t)(k0 + j) * NC_ + n]) : (short)0;
  *(bh8*)(Cpk + (size_t)idx * 8) = o;
}

// ---------------- pack W^T (K=1792 x N=448) into B-frag layout ----------------
__global__ void wpack_kernel(const float* __restrict__ W, short* __restrict__ Wpk) {
  int idx = blockIdx.x * 256 + threadIdx.x;       // NCHP_*KCP_*64 = 100352 exact
  int ln = idx & 63;
  int kc = (idx >> 6) % KCP_;
  int nc = idx / (KCP_ * 64);
  int n  = nc * 16 + (ln & 15);
  int k0 = kc * 32 + ((ln >> 4) << 3);
  bh8 o;
#pragma unroll
  for (int j = 0; j < 8; ++j) o[j] = f2bf(W[(size_t)n * DIN_ + k0 + j]);
  *(bh8*)(Wpk + (size_t)idx * 8) = o;
}

// ======== phi: A-frags direct from desc; bias+coords fused; in-place phipack ========
__global__ __launch_bounds__(256) void phi_mfma(
    const short* __restrict__ desc, const short* __restrict__ Wpk,
    const float* __restrict__ cw, const float* __restrict__ cb,
    short* __restrict__ phip /* aliases desc */) {
  __shared__ __align__(16) float Dt[16 * DTS_];   // 28.9 KB
  const int wv = threadIdx.x >> 6, ln = threadIdx.x & 63;
  const int pix0 = blockIdx.x * 32;
  const short* aptr = desc + ((size_t)(pix0 + (ln & 15))) * KD_ + ((ln >> 4) << 3);

  f32x4 acc[2][7];
#pragma unroll
  for (int rc = 0; rc < 2; ++rc)
#pragma unroll
    for (int i = 0; i < 7; ++i) acc[rc][i] = (f32x4){0.f, 0.f, 0.f, 0.f};

  const short* bbase = Wpk + (size_t)(wv * 7) * (KCP_ * 512) + ln * 8;
  for (int kc = 0; kc < KCP_; ++kc) {
    bh8 a0 = *(const bh8*)(aptr + kc * 32);
    bh8 a1 = *(const bh8*)(aptr + 16 * KD_ + kc * 32);
    const short* bp = bbase + kc * 512;
#pragma unroll
    for (int i = 0; i < 7; ++i) {
      bh8 bfr = *(const bh8*)(bp + (size_t)i * (KCP_ * 512));
      acc[0][i] = __builtin_amdgcn_mfma_f32_16x16x32_bf16(a0, bfr, acc[0][i], 0, 0, 0);
      acc[1][i] = __builtin_amdgcn_mfma_f32_16x16x32_bf16(a1, bfr, acc[1][i], 0, 0, 0);
    }
  }

  for (int rc = 0; rc < 2; ++rc) {
    __syncthreads();   // rc=0: all desc reads done; rc=1: all rc=0 repack reads done
#pragma unroll
    for (int i = 0; i < 7; ++i) {
      int col = (wv * 7 + i) * 16 + (ln & 15);
      float bias = cb[col];
      float wx = cw[(size_t)col * DIN_ + 1792];
      float wy = cw[(size_t)col * DIN_ + 1793];
#pragma unroll
      for (int r = 0; r < 4; ++r) {
        int row = ((ln >> 4) << 2) + r;
        int pid = pix0 + rc * 16 + row;
        int hw = pid % HW_;
        int hh = hw / 56, ww = hw % 56;
        float xx = (float)hh * (2.0f / 55.0f) - 1.0f;
        float yy = (float)ww * (2.0f / 55.0f) - 1.0f;
        Dt[row * DTS_ + col] = acc[rc][i][r] + bias + wx * xx + wy * yy;
      }
    }
    __syncthreads();
    short* op = phip + (size_t)(blockIdx.x * 2 + rc) * PCH_;
    for (int item = threadIdx.x; item < KCD_ * 64; item += 256) {
      int kc = item >> 6, lp = item & 63;
      int m = lp & 15, k0 = kc * 32 + ((lp >> 4) << 3);
      bh8 o;
#pragma unroll
      for (int j = 0; j < 8; ++j) o[j] = f2bf(Dt[m * DTS_ + k0 + j]);
      *(bh8*)(op + (size_t)item * 8) = o;
    }
  }
}

// ======== dist v10: LDS-shared B (4 waves), scalarized state, dbuf staging ========
// Block = 64 px (4 waves x 16-px chunk) x one N-quarter (50 chunks, 25 pairs).
// L2 traffic 4.3 GB -> 1.1 GB (each B byte shared by 4 waves).
// amdgpu_waves_per_eu(2,2): LDS caps 2 blocks/CU anyway -> allocator has no
// occupancy incentive to spill (R5-R11 root cause).
__device__ __forceinline__ void insert3(float& t0, float& t1, float& t2, float v) {
  if (v < t2) {
    if (v < t1) {
      t2 = t1;
      if (v < t0) { t1 = t0; t0 = v; } else t1 = v;
    } else t2 = v;
  }
}
__device__ __forceinline__ void merge3(float& a0, float& a1, float& a2,
                                       float b0, float b1, float b2) {
  float lo0 = fminf(a0, b0), hi0 = fmaxf(a0, b0);
  float lo1 = fminf(a1, b1), hi1 = fmaxf(a1, b1);
  float lo2 = fminf(a2, b2);
  a0 = lo0;
  a1 = fminf(hi0, lo1);
  a2 = fminf(fmaxf(hi0, lo1), fminf(hi1, lo2));
}
__device__ __forceinline__ float sumsq8(bh8 a, float s) {
#pragma unroll
  for (int j = 0; j < 8; ++j) { float v = bf2f(a[j]); s = fmaf(v, v, s); }
  return s;
}

#define AFRAG_LIST(X) X(0) X(1) X(2) X(3) X(4) X(5) X(6) X(7) X(8) X(9) X(10) X(11) X(12) X(13)

__global__ __launch_bounds__(256) __attribute__((amdgpu_waves_per_eu(2, 2)))
void dist_part(const short* __restrict__ phip, const short* __restrict__ Cpk,
               const float* __restrict__ c2g, float* __restrict__ part) {
  __shared__ __align__(16) short sB[2][2 * CHS_];   // 2 x 28 KB double buffer
  const int wv = threadIdx.x >> 6, ln = threadIdx.x & 63;
  const int pg = blockIdx.x >> 2;          // 64-pixel group (0..391)
  const int quarter = blockIdx.x & 3;
  const int chunk = pg * 4 + wv;           // this wave's 16-pixel chunk
  const int nc0 = quarter * QCH_;

  // A-frags: 14 named registers (proven no-spill shape)
  const short* ap = phip + (size_t)chunk * PCH_ + ln * 8;
#define LOADA(i) bh8 A##i = *(const bh8*)(ap + (i) * 512);
  AFRAG_LIST(LOADA)
#undef LOADA

  // f2 per pixel row
  float sum = 0.f;
#define SQ(i) sum = sumsq8(A##i, sum);
  AFRAG_LIST(SQ)
#undef SQ
  sum += __shfl_xor(sum, 16, 64);
  sum += __shfl_xor(sum, 32, 64);
  const int rb = (ln >> 4) << 2;
  float f2r0 = __shfl(sum, rb + 0, 64);
  float f2r1 = __shfl(sum, rb + 1, 64);
  float f2r2 = __shfl(sum, rb + 2, 64);
  float f2r3 = __shfl(sum, rb + 3, 64);

  float t00 = 1e30f, t01 = 1e30f, t02 = 1e30f;
  float t10 = 1e30f, t11 = 1e30f, t12 = 1e30f;
  float t20 = 1e30f, t21 = 1e30f, t22 = 1e30f;
  float t30 = 1e30f, t31 = 1e30f, t32 = 1e30f;

  const short* csrc = Cpk + (size_t)nc0 * CHS_;     // this block's quarter
  const float* c2base = c2g + (size_t)nc0 * 16 + (ln & 15);

  // stage pair 0 (28 KB): 7 width-16 global_load_lds calls per wave, uniform
#pragma unroll
  for (int c = 0; c < 7; ++c) {
    int slot = wv * 7 + c;
    __builtin_amdgcn_global_load_lds(
        (const __attribute__((address_space(1))) unsigned int*)(csrc + slot * 512 + ln * 8),
        (__attribute__((address_space(3))) unsigned int*)(&sB[0][slot * 512]),
        16, 0, 0);
  }

  for (int p = 0; p < 25; ++p) {
    __syncthreads();   // staging of buf[p&1] complete; prior compute done
    if (p + 1 < 25) {
      const short* src = csrc + (size_t)(p + 1) * (2 * CHS_);
#pragma unroll
      for (int c = 0; c < 7; ++c) {
        int slot = wv * 7 + c;
        __builtin_amdgcn_global_load_lds(
            (const __attribute__((address_space(1))) unsigned int*)(src + slot * 512 + ln * 8),
            (__attribute__((address_space(3))) unsigned int*)(&sB[(p + 1) & 1][slot * 512]),
            16, 0, 0);
      }
    }
    const short* bufA = &sB[p & 1][0] + ln * 8;
    const short* bufB = bufA + CHS_;
    f32x4 accA = {0.f, 0.f, 0.f, 0.f}, accB = {0.f, 0.f, 0.f, 0.f};
#define MF(kc) { \
    bh8 bA = *(const bh8*)(bufA + (kc) * 512); \
    bh8 bB = *(const bh8*)(bufB + (kc) * 512); \
    accA = __builtin_amdgcn_mfma_f32_16x16x32_bf16(A##kc, bA, accA, 0, 0, 0); \
    accB = __builtin_amdgcn_mfma_f32_16x16x32_bf16(A##kc, bB, accB, 0, 0, 0); }
    AFRAG_LIST(MF)
#undef MF
    float c2A = c2base[(size_t)(2 * p) * 16];
    float c2B = c2base[(size_t)(2 * p + 1) * 16];
    insert3(t00, t01, t02, f2r0 + c2A - 2.0f * accA[0]);
    insert3(t10, t11, t12, f2r1 + c2A - 2.0f * accA[1]);
    insert3(t20, t21, t22, f2r2 + c2A - 2.0f * accA[2]);
    insert3(t30, t31, t32, f2r3 + c2A - 2.0f * accA[3]);
    insert3(t00, t01, t02, f2r0 + c2B - 2.0f * accB[0]);
    insert3(t10, t11, t12, f2r1 + c2B - 2.0f * accB[1]);
    insert3(t20, t21, t22, f2r2 + c2B - 2.0f * accB[2]);
    insert3(t30, t31, t32, f2r3 + c2B - 2.0f * accB[3]);
  }

  // merge the 16 column-lanes (same pixel rows, different centers) — shfl only
#pragma unroll
  for (int m = 1; m <= 8; m <<= 1) {
    float b0, b1, b2;
    b0 = __shfl_xor(t00, m, 64); b1 = __shfl_xor(t01, m, 64); b2 = __shfl_xor(t02, m, 64);
    merge3(t00, t01, t02, b0, b1, b2);
    b0 = __shfl_xor(t10, m, 64); b1 = __shfl_xor(t11, m, 64); b2 = __shfl_xor(t12, m, 64);
    merge3(t10, t11, t12, b0, b1, b2);
    b0 = __shfl_xor(t20, m, 64); b1 = __shfl_xor(t21, m, 64); b2 = __shfl_xor(t22, m, 64);
    merge3(t20, t21, t22, b0, b1, b2);
    b0 = __shfl_xor(t30, m, 64); b1 = __shfl_xor(t31, m, 64); b2 = __shfl_xor(t32, m, 64);
    merge3(t30, t31, t32, b0, b1, b2);
  }

  if ((ln & 15) == 0) {
    float* qp = part + ((size_t)(chunk * 16 + rb)) * 16 + quarter * 4;
    qp[0]  = t00; qp[1]  = t01; qp[2]  = t02;
    qp[16] = t10; qp[17] = t11; qp[18] = t12;
    qp[32] = t20; qp[33] = t21; qp[34] = t22;
    qp[48] = t30; qp[49] = t31; qp[50] = t32;
  }
}

// ======== merge: combine 4 partial triples per pixel, softmin score ========
__global__ __launch_bounds__(256) void merge_kernel(const float* __restrict__ part,
                                                    float* __restrict__ out) {
  int p = blockIdx.x * 256 + threadIdx.x;   // 25088 exact
  const float* q = part + (size_t)p * 16;
  float a0 = q[0], a1 = q[1], a2 = q[2];
#pragma unroll
  for (int w = 1; w < 4; ++w) merge3(a0, a1, a2, q[w * 4], q[w * 4 + 1], q[w * 4 + 2]);
  float d0 = sqrtf(fmaxf(a0, 0.f));
  float d1 = sqrtf(fmaxf(a1, 0.f));
  float d2 = sqrtf(fmaxf(a2, 0.f));
  float s0 = 1.0f / (1.0f + expf(d0 - d1) + expf(d0 - d2));
  out[p] = s0 * d0;
}

// ---------------- launch ----------------
extern "C" void kernel_launch(void* const* d_in, const int* in_sizes, int n_in,
                              void* d_out, int out_size, void* d_ws, size_t ws_size,
                              hipStream_t stream) {
  const float* p0 = (const float*)d_in[0];
  const float* p1 = (const float*)d_in[1];
  const float* p2 = (const float*)d_in[2];
  const float* cw = (const float*)d_in[3];
  const float* cb = (const float*)d_in[4];
  const float* C  = (const float*)d_in[5];
  float* out = (float*)d_out;

  short* desc = (short*)d_ws;                                   // 44,957,696 shorts
  short* Cpk  = desc + (size_t)25088 * KD_;                     //  1,433,600 shorts (padded)
  short* Wpk  = Cpk + (size_t)NCPAD_ * KCD_ * 512;              //    802,816 shorts
  float* c2   = (float*)(Wpk + (size_t)NCHP_ * KCP_ * 512);     //      3,200 floats (padded)
  float* part = c2 + NCPAD_ * 16;                               //    401,408 floats (~1.6 MB)

  desc0_kernel<<<dim3(4, 56, 8),  256, 0, stream>>>(p0, desc);
  desc1_kernel<<<dim3(8, 56, 8),  256, 0, stream>>>(p1, desc);
  desc2_kernel<<<dim3(16, 56, 8), 256, 0, stream>>>(p2, desc);
  cent2_kernel<<<(NCPAD_ * 16 + 255) / 256, 256, 0, stream>>>(C, c2);
  cpack_kernel<<<NCPAD_ * KCD_ * 64 / 256, 256, 0, stream>>>(C, Cpk);
  wpack_kernel<<<NCHP_ * KCP_ * 64 / 256, 256, 0, stream>>>(cw, Wpk);
  phi_mfma<<<25088 / 32, 256, 0, stream>>>(desc, Wpk, cw, cb, desc);
  dist_part<<<1568, 256, 0, stream>>>(desc, Cpk, c2, part);
  merge_kernel<<<25088 / 256, 256, 0, stream>>>(part, out);
}

// Round 13
// 689.677 us; speedup vs baseline: 1.0682x; 1.0682x over previous
//
#include <hip/hip_runtime.h>
#include <math.h>

// ---------------- problem constants ----------------
#define B_    8
#define H_    56
#define W_    56
#define HW_   3136
#define C0_   256
#define C1_   512
#define C2_   1024
#define DIN_  1794      // raw conv_w K (includes 2 coord cols, folded into epilogue)
#define KD_   1792      // descriptor K (GEMM K), 56 chunks of 32
#define KCP_  56        // phi K-chunks
#define DOUT_ 448
#define NCHP_ 28        // phi N-chunks (448/16)
#define NC_   3136      // centers
#define NCHD_ 196       // dist N-chunks (3136/16)
#define NCPAD_ 200      // padded to 4 quarters of 50
#define QCH_  50        // N-chunks per quarter
#define KCD_  14        // dist K-chunks (448/32)
#define DTS_  452       // LDS D-tile row stride (floats)
#define PCH_  28672     // phip chunk stride in shorts (in-place alias of desc pixels)
#define CHS_  7168      // one B-chunk in shorts (14*512)

typedef __attribute__((ext_vector_type(8))) short bh8;
typedef __attribute__((ext_vector_type(4))) float f32x4;

__device__ __forceinline__ short f2bf(float f) {
  union { float f; unsigned u; } v; v.f = f;
  unsigned r = v.u + 0x7fffu + ((v.u >> 16) & 1u);
  return (short)(r >> 16);
}
__device__ __forceinline__ float bf2f(short s) {
  union { unsigned u; float f; } v; v.u = ((unsigned)(unsigned short)s) << 16;
  return v.f;
}

// ======== desc0: pool(p0) -> desc[:, 0:256], transposed, bf16 ========
__global__ __launch_bounds__(256) void desc0_kernel(const float* __restrict__ p0,
                                                    short* __restrict__ desc) {
  __shared__ float sv[64 * 57];
  const int c0 = blockIdx.x * 64, h = blockIdx.y, b = blockIdx.z;
  for (int item = threadIdx.x; item < 64 * 56; item += 256) {
    int x = item % 56, c = item / 56;
    const float* src = p0 + (((size_t)(b * C0_ + c0 + c)) * 56 + h) * 56 + x;
    float s = src[0];
    if (h > 0)  s += src[-56];
    if (h < 55) s += src[56];
    sv[c * 57 + x] = s;
  }
  __syncthreads();
  for (int item = threadIdx.x; item < 56 * 8; item += 256) {
    int g = item & 7, w = item >> 3;
    bh8 o;
#pragma unroll
    for (int j = 0; j < 8; ++j) {
      const float* s0 = sv + (g * 8 + j) * 57;
      float v = s0[w];
      if (w > 0)  v += s0[w - 1];
      if (w < 55) v += s0[w + 1];
      o[j] = f2bf(v * (1.0f / 9.0f));
    }
    size_t pid = (size_t)b * HW_ + h * 56 + w;
    *(bh8*)(desc + pid * KD_ + c0 + g * 8) = o;
  }
}

// ======== desc1: pool(p1)+bilinear x2 -> desc[:, 256:768] ========
__global__ __launch_bounds__(256) void desc1_kernel(const float* __restrict__ p1,
                                                    short* __restrict__ desc) {
  __shared__ float sv[2 * 64 * 29];
  const int c0 = blockIdx.x * 64, h = blockIdx.y, b = blockIdx.z;
  float sy = (h + 0.5f) * 0.5f - 0.5f;
  float fyf = floorf(sy);
  float fy = sy - fyf;
  int iy = (int)fyf;
  int pya = min(max(iy, 0), 27), pyb = min(max(iy + 1, 0), 27);
  for (int item = threadIdx.x; item < 64 * 2 * 28; item += 256) {
    int x = item % 28;
    int pr = (item / 28) & 1;
    int c = item / 56;
    int r = pr ? pyb : pya;
    const float* src = p1 + (((size_t)(b * C1_ + c0 + c)) * 28 + r) * 28 + x;
    float s = src[0];
    if (r > 0)  s += src[-28];
    if (r < 27) s += src[28];
    sv[pr * (64 * 29) + c * 29 + x] = s;
  }
  __syncthreads();
  for (int item = threadIdx.x; item < 56 * 8; item += 256) {
    int g = item & 7, w = item >> 3;
    float sx = (w + 0.5f) * 0.5f - 0.5f;
    float fxf = floorf(sx);
    float fx = sx - fxf;
    int ix = (int)fxf;
    int x0 = min(max(ix, 0), 27), x1 = min(max(ix + 1, 0), 27);
    bh8 o;
#pragma unroll
    for (int j = 0; j < 8; ++j) {
      const float* s0 = sv + (g * 8 + j) * 29;
      const float* s1 = s0 + 64 * 29;
      float p00 = s0[x0] + (x0 > 0 ? s0[x0 - 1] : 0.f) + (x0 < 27 ? s0[x0 + 1] : 0.f);
      float p01 = s0[x1] + (x1 > 0 ? s0[x1 - 1] : 0.f) + (x1 < 27 ? s0[x1 + 1] : 0.f);
      float p10 = s1[x0] + (x0 > 0 ? s1[x0 - 1] : 0.f) + (x0 < 27 ? s1[x0 + 1] : 0.f);
      float p11 = s1[x1] + (x1 > 0 ? s1[x1 - 1] : 0.f) + (x1 < 27 ? s1[x1 + 1] : 0.f);
      float top = p00 + fx * (p01 - p00);
      float bot = p10 + fx * (p11 - p10);
      o[j] = f2bf((top + fy * (bot - top)) * (1.0f / 9.0f));
    }
    size_t pid = (size_t)b * HW_ + h * 56 + w;
    *(bh8*)(desc + pid * KD_ + C0_ + c0 + g * 8) = o;
  }
}

// ======== desc2: pool(p2)+bilinear x4 -> desc[:, 768:1792] ========
__global__ __launch_bounds__(256) void desc2_kernel(const float* __restrict__ p2,
                                                    short* __restrict__ desc) {
  __shared__ float sv[2 * 64 * 15];
  const int c0 = blockIdx.x * 64, h = blockIdx.y, b = blockIdx.z;
  float sy = (h + 0.5f) * 0.25f - 0.5f;
  float fyf = floorf(sy);
  float fy = sy - fyf;
  int iy = (int)fyf;
  int pya = min(max(iy, 0), 13), pyb = min(max(iy + 1, 0), 13);
  for (int item = threadIdx.x; item < 64 * 2 * 14; item += 256) {
    int x = item % 14;
    int pr = (item / 14) & 1;
    int c = item / 28;
    int r = pr ? pyb : pya;
    const float* src = p2 + (((size_t)(b * C2_ + c0 + c)) * 14 + r) * 14 + x;
    float s = src[0];
    if (r > 0)  s += src[-14];
    if (r < 13) s += src[14];
    sv[pr * (64 * 15) + c * 15 + x] = s;
  }
  __syncthreads();
  for (int item = threadIdx.x; item < 56 * 8; item += 256) {
    int g = item & 7, w = item >> 3;
    float sx = (w + 0.5f) * 0.25f - 0.5f;
    float fxf = floorf(sx);
    float fx = sx - fxf;
    int ix = (int)fxf;
    int x0 = min(max(ix, 0), 13), x1 = min(max(ix + 1, 0), 13);
    bh8 o;
#pragma unroll
    for (int j = 0; j < 8; ++j) {
      const float* s0 = sv + (g * 8 + j) * 15;
      const float* s1 = s0 + 64 * 15;
      float p00 = s0[x0] + (x0 > 0 ? s0[x0 - 1] : 0.f) + (x0 < 13 ? s0[x0 + 1] : 0.f);
      float p01 = s0[x1] + (x1 > 0 ? s0[x1 - 1] : 0.f) + (x1 < 13 ? s0[x1 + 1] : 0.f);
      float p10 = s1[x0] + (x0 > 0 ? s1[x0 - 1] : 0.f) + (x0 < 13 ? s1[x0 + 1] : 0.f);
      float p11 = s1[x1] + (x1 > 0 ? s1[x1 - 1] : 0.f) + (x1 < 13 ? s1[x1 + 1] : 0.f);
      float top = p00 + fx * (p01 - p00);
      float bot = p10 + fx * (p11 - p10);
      o[j] = f2bf((top + fy * (bot - top)) * (1.0f / 9.0f));
    }
    size_t pid = (size_t)b * HW_ + h * 56 + w;
    *(bh8*)(desc + pid * KD_ + C0_ + C1_ + c0 + g * 8) = o;
  }
}

// ---------------- |c_j|^2 (bf16-rounded), padded: j>=NC_ -> 1e30 ----------------
__global__ void cent2_kernel(const float* __restrict__ C, float* __restrict__ c2) {
  int j = blockIdx.x * blockDim.x + threadIdx.x;
  if (j >= NCPAD_ * 16) return;
  if (j >= NC_) { c2[j] = 1e30f; return; }
  float s = 0.f;
  for (int d = 0; d < DOUT_; ++d) {
    float v = bf2f(f2bf(C[(size_t)d * NC_ + j]));
    s = fmaf(v, v, s);
  }
  c2[j] = s;
}

// ---------------- pack C into B-frag layout, padded to 200 N-chunks ----------------
__global__ void cpack_kernel(const float* __restrict__ C, short* __restrict__ Cpk) {
  int idx = blockIdx.x * 256 + threadIdx.x;       // NCPAD_*KCD_*64 = 179200 exact
  int ln = idx & 63;
  int kc = (idx >> 6) % KCD_;
  int nc = idx / (KCD_ * 64);
  int n  = nc * 16 + (ln & 15);
  int k0 = kc * 32 + ((ln >> 4) << 3);
  bh8 o;
#pragma unroll
  for (int j = 0; j < 8; ++j) o[j] = (n < NC_) ? f2bf(C[(size_t)(k0 + j) * NC_ + n]) : (short)0;
  *(bh8*)(Cpk + (size_t)idx * 8) = o;
}

// ---------------- pack W^T (K=1792 x N=448) into B-frag layout ----------------
__global__ void wpack_kernel(const float* __restrict__ W, short* __restrict__ Wpk) {
  int idx = blockIdx.x * 256 + threadIdx.x;       // NCHP_*KCP_*64 = 100352 exact
  int ln = idx & 63;
  int kc = (idx >> 6) % KCP_;
  int nc = idx / (KCP_ * 64);
  int n  = nc * 16 + (ln & 15);
  int k0 = kc * 32 + ((ln >> 4) << 3);
  bh8 o;
#pragma unroll
  for (int j = 0; j < 8; ++j) o[j] = f2bf(W[(size_t)n * DIN_ + k0 + j]);
  *(bh8*)(Wpk + (size_t)idx * 8) = o;
}

// ======== phi: A-frags direct from desc; bias+coords fused; in-place phipack ========
__global__ __launch_bounds__(256) void phi_mfma(
    const short* __restrict__ desc, const short* __restrict__ Wpk,
    const float* __restrict__ cw, const float* __restrict__ cb,
    short* __restrict__ phip /* aliases desc */) {
  __shared__ __align__(16) float Dt[16 * DTS_];   // 28.9 KB
  const int wv = threadIdx.x >> 6, ln = threadIdx.x & 63;
  const int pix0 = blockIdx.x * 32;
  const short* aptr = desc + ((size_t)(pix0 + (ln & 15))) * KD_ + ((ln >> 4) << 3);

  f32x4 acc[2][7];
#pragma unroll
  for (int rc = 0; rc < 2; ++rc)
#pragma unroll
    for (int i = 0; i < 7; ++i) acc[rc][i] = (f32x4){0.f, 0.f, 0.f, 0.f};

  const short* bbase = Wpk + (size_t)(wv * 7) * (KCP_ * 512) + ln * 8;
  for (int kc = 0; kc < KCP_; ++kc) {
    bh8 a0 = *(const bh8*)(aptr + kc * 32);
    bh8 a1 = *(const bh8*)(aptr + 16 * KD_ + kc * 32);
    const short* bp = bbase + kc * 512;
#pragma unroll
    for (int i = 0; i < 7; ++i) {
      bh8 bfr = *(const bh8*)(bp + (size_t)i * (KCP_ * 512));
      acc[0][i] = __builtin_amdgcn_mfma_f32_16x16x32_bf16(a0, bfr, acc[0][i], 0, 0, 0);
      acc[1][i] = __builtin_amdgcn_mfma_f32_16x16x32_bf16(a1, bfr, acc[1][i], 0, 0, 0);
    }
  }

  for (int rc = 0; rc < 2; ++rc) {
    __syncthreads();   // rc=0: all desc reads done; rc=1: all rc=0 repack reads done
#pragma unroll
    for (int i = 0; i < 7; ++i) {
      int col = (wv * 7 + i) * 16 + (ln & 15);
      float bias = cb[col];
      float wx = cw[(size_t)col * DIN_ + 1792];
      float wy = cw[(size_t)col * DIN_ + 1793];
#pragma unroll
      for (int r = 0; r < 4; ++r) {
        int row = ((ln >> 4) << 2) + r;
        int pid = pix0 + rc * 16 + row;
        int hw = pid % HW_;
        int hh = hw / 56, ww = hw % 56;
        float xx = (float)hh * (2.0f / 55.0f) - 1.0f;
        float yy = (float)ww * (2.0f / 55.0f) - 1.0f;
        Dt[row * DTS_ + col] = acc[rc][i][r] + bias + wx * xx + wy * yy;
      }
    }
    __syncthreads();
    short* op = phip + (size_t)(blockIdx.x * 2 + rc) * PCH_;
    for (int item = threadIdx.x; item < KCD_ * 64; item += 256) {
      int kc = item >> 6, lp = item & 63;
      int m = lp & 15, k0 = kc * 32 + ((lp >> 4) << 3);
      bh8 o;
#pragma unroll
      for (int j = 0; j < 8; ++j) o[j] = f2bf(Dt[m * DTS_ + k0 + j]);
      *(bh8*)(op + (size_t)item * 8) = o;
    }
  }
}

// ======== dist v11: R11's proven paired body, quarter-N mapping ========
// Block = one 16-px chunk; 4 waves = 4 N-quarters (25 pairs each, padded bank).
// No LDS, no barrier. A reads x4 shared via L1. 1568 blocks -> 24.5 waves/CU
// of continuous streaming: ~2x the in-flight bytes of R11 (Little's law fix).
__device__ __forceinline__ void insert3(float& t0, float& t1, float& t2, float v) {
  if (v < t2) {
    if (v < t1) {
      t2 = t1;
      if (v < t0) { t1 = t0; t0 = v; } else t1 = v;
    } else t2 = v;
  }
}
__device__ __forceinline__ void merge3(float& a0, float& a1, float& a2,
                                       float b0, float b1, float b2) {
  float lo0 = fminf(a0, b0), hi0 = fmaxf(a0, b0);
  float lo1 = fminf(a1, b1), hi1 = fmaxf(a1, b1);
  float lo2 = fminf(a2, b2);
  a0 = lo0;
  a1 = fminf(hi0, lo1);
  a2 = fminf(fmaxf(hi0, lo1), fminf(hi1, lo2));
}
__device__ __forceinline__ float sumsq8(bh8 a, float s) {
#pragma unroll
  for (int j = 0; j < 8; ++j) { float v = bf2f(a[j]); s = fmaf(v, v, s); }
  return s;
}

#define AFRAG_LIST(X) X(0) X(1) X(2) X(3) X(4) X(5) X(6) X(7) X(8) X(9) X(10) X(11) X(12) X(13)

__global__ __launch_bounds__(256, 4) void dist_part(
    const short* __restrict__ phip, const short* __restrict__ Cpk,
    const float* __restrict__ c2g, float* __restrict__ part) {
  const int wv = threadIdx.x >> 6, ln = threadIdx.x & 63;
  const int chunk = blockIdx.x;            // one 16-pixel chunk per block
  const int nc0 = wv * QCH_;               // this wave's N-quarter

  const short* ap = phip + (size_t)chunk * PCH_ + ln * 8;
#define LOADA(i) bh8 A##i = *(const bh8*)(ap + (i) * 512);
  AFRAG_LIST(LOADA)
#undef LOADA

  // f2 per pixel row (self-consistent with bf16 MFMA dot)
  float sum = 0.f;
#define SQ(i) sum = sumsq8(A##i, sum);
  AFRAG_LIST(SQ)
#undef SQ
  sum += __shfl_xor(sum, 16, 64);
  sum += __shfl_xor(sum, 32, 64);
  const int rb = (ln >> 4) << 2;
  float f2r0 = __shfl(sum, rb + 0, 64);
  float f2r1 = __shfl(sum, rb + 1, 64);
  float f2r2 = __shfl(sum, rb + 2, 64);
  float f2r3 = __shfl(sum, rb + 3, 64);

  float t00 = 1e30f, t01 = 1e30f, t02 = 1e30f;
  float t10 = 1e30f, t11 = 1e30f, t12 = 1e30f;
  float t20 = 1e30f, t21 = 1e30f, t22 = 1e30f;
  float t30 = 1e30f, t31 = 1e30f, t32 = 1e30f;

  const short* bbase = Cpk + (size_t)nc0 * CHS_ + ln * 8;
  const float* c2base = c2g + (size_t)nc0 * 16 + (ln & 15);
  for (int i = 0; i < QCH_ / 2; ++i) {
    const short* bpA = bbase + (size_t)(2 * i) * CHS_;
    const short* bpB = bpA + CHS_;
    f32x4 accA = {0.f, 0.f, 0.f, 0.f}, accB = {0.f, 0.f, 0.f, 0.f};
#define MF(kc) { \
    bh8 bA = *(const bh8*)(bpA + (kc) * 512); \
    bh8 bB = *(const bh8*)(bpB + (kc) * 512); \
    accA = __builtin_amdgcn_mfma_f32_16x16x32_bf16(A##kc, bA, accA, 0, 0, 0); \
    accB = __builtin_amdgcn_mfma_f32_16x16x32_bf16(A##kc, bB, accB, 0, 0, 0); }
    AFRAG_LIST(MF)
#undef MF
    float c2A = c2base[(size_t)(2 * i) * 16];
    float c2B = c2base[(size_t)(2 * i + 1) * 16];
    insert3(t00, t01, t02, f2r0 + c2A - 2.0f * accA[0]);
    insert3(t10, t11, t12, f2r1 + c2A - 2.0f * accA[1]);
    insert3(t20, t21, t22, f2r2 + c2A - 2.0f * accA[2]);
    insert3(t30, t31, t32, f2r3 + c2A - 2.0f * accA[3]);
    insert3(t00, t01, t02, f2r0 + c2B - 2.0f * accB[0]);
    insert3(t10, t11, t12, f2r1 + c2B - 2.0f * accB[1]);
    insert3(t20, t21, t22, f2r2 + c2B - 2.0f * accB[2]);
    insert3(t30, t31, t32, f2r3 + c2B - 2.0f * accB[3]);
  }

  // merge the 16 column-lanes (same pixel rows, different centers) — shfl only
#pragma unroll
  for (int m = 1; m <= 8; m <<= 1) {
    float b0, b1, b2;
    b0 = __shfl_xor(t00, m, 64); b1 = __shfl_xor(t01, m, 64); b2 = __shfl_xor(t02, m, 64);
    merge3(t00, t01, t02, b0, b1, b2);
    b0 = __shfl_xor(t10, m, 64); b1 = __shfl_xor(t11, m, 64); b2 = __shfl_xor(t12, m, 64);
    merge3(t10, t11, t12, b0, b1, b2);
    b0 = __shfl_xor(t20, m, 64); b1 = __shfl_xor(t21, m, 64); b2 = __shfl_xor(t22, m, 64);
    merge3(t20, t21, t22, b0, b1, b2);
    b0 = __shfl_xor(t30, m, 64); b1 = __shfl_xor(t31, m, 64); b2 = __shfl_xor(t32, m, 64);
    merge3(t30, t31, t32, b0, b1, b2);
  }

  if ((ln & 15) == 0) {
    float* qp = part + ((size_t)(chunk * 16 + rb)) * 16 + wv * 4;
    qp[0]  = t00; qp[1]  = t01; qp[2]  = t02;
    qp[16] = t10; qp[17] = t11; qp[18] = t12;
    qp[32] = t20; qp[33] = t21; qp[34] = t22;
    qp[48] = t30; qp[49] = t31; qp[50] = t32;
  }
}

// ======== merge: combine 4 partial triples per pixel, softmin score ========
__global__ __launch_bounds__(256) void merge_kernel(const float* __restrict__ part,
                                                    float* __restrict__ out) {
  int p = blockIdx.x * 256 + threadIdx.x;   // 25088 exact
  const float* q = part + (size_t)p * 16;
  float a0 = q[0], a1 = q[1], a2 = q[2];
#pragma unroll
  for (int w = 1; w < 4; ++w) merge3(a0, a1, a2, q[w * 4], q[w * 4 + 1], q[w * 4 + 2]);
  float d0 = sqrtf(fmaxf(a0, 0.f));
  float d1 = sqrtf(fmaxf(a1, 0.f));
  float d2 = sqrtf(fmaxf(a2, 0.f));
  float s0 = 1.0f / (1.0f + expf(d0 - d1) + expf(d0 - d2));
  out[p] = s0 * d0;
}

// ---------------- launch ----------------
extern "C" void kernel_launch(void* const* d_in, const int* in_sizes, int n_in,
                              void* d_out, int out_size, void* d_ws, size_t ws_size,
                              hipStream_t stream) {
  const float* p0 = (const float*)d_in[0];
  const float* p1 = (const float*)d_in[1];
  const float* p2 = (const float*)d_in[2];
  const float* cw = (const float*)d_in[3];
  const float* cb = (const float*)d_in[4];
  const float* C  = (const float*)d_in[5];
  float* out = (float*)d_out;

  short* desc = (short*)d_ws;                                   // 44,957,696 shorts
  short* Cpk  = desc + (size_t)25088 * KD_;                     //  1,433,600 shorts (padded)
  short* Wpk  = Cpk + (size_t)NCPAD_ * KCD_ * 512;              //    802,816 shorts
  float* c2   = (float*)(Wpk + (size_t)NCHP_ * KCP_ * 512);     //      3,200 floats (padded)
  float* part = c2 + NCPAD_ * 16;                               //    401,408 floats (~1.6 MB)

  desc0_kernel<<<dim3(4, 56, 8),  256, 0, stream>>>(p0, desc);
  desc1_kernel<<<dim3(8, 56, 8),  256, 0, stream>>>(p1, desc);
  desc2_kernel<<<dim3(16, 56, 8), 256, 0, stream>>>(p2, desc);
  cent2_kernel<<<(NCPAD_ * 16 + 255) / 256, 256, 0, stream>>>(C, c2);
  cpack_kernel<<<NCPAD_ * KCD_ * 64 / 256, 256, 0, stream>>>(C, Cpk);
  wpack_kernel<<<NCHP_ * KCP_ * 64 / 256, 256, 0, stream>>>(cw, Wpk);
  phi_mfma<<<25088 / 32, 256, 0, stream>>>(desc, Wpk, cw, cb, desc);
  dist_part<<<25088 / 16, 256, 0, stream>>>(desc, Cpk, c2, part);
  merge_kernel<<<25088 / 256, 256, 0, stream>>>(part, out);
}